// Round 27
// baseline (40.779 us; speedup 1.0000x reference)
//
#include <hip/hip_runtime.h>
#include <hip/hip_bf16.h>

#define HH 192
#define WW 192
#define HOUT 190
#define NCH 64
#define W2_N (64 * 9 * 64)

typedef __attribute__((ext_vector_type(8))) short bf16x8;
typedef __attribute__((ext_vector_type(4))) float f32x4;

static __device__ __forceinline__ ushort f2bf(float f) {
    __hip_bfloat16 h = __float2bfloat16(f);   // RNE
    return *reinterpret_cast<ushort*>(&h);
}
static __device__ __forceinline__ uint pack2bf(float lo, float hi) {
    return (uint)f2bf(lo) | ((uint)f2bf(hi) << 16);
}

// W2[o][tap][c] = sum_t (conn[o*16+t]==c) * w[(o*16+t)*9 + tap], bf16.
__global__ __launch_bounds__(256) void build_w2(const float* __restrict__ w,
                                                const int* __restrict__ conn,
                                                ushort* __restrict__ w2) {
    int idx = blockIdx.x * 256 + threadIdx.x;
    if (idx >= W2_N) return;
    int o = idx / 576, rem = idx - o * 576, tap = rem >> 6, c = rem & 63;
    float s = 0.f;
    #pragma unroll
    for (int t = 0; t < 16; ++t) {
        int k = o * 16 + t;
        if (conn[k] == c) s += w[k * 9 + tap];
    }
    w2[idx] = f2bf(s);
}

// Dense 64->64 3x3 conv via mfma_f32_16x16x32_bf16, operand-swapped
// (A = W2 -> D rows = o-quads, D lanes = contiguous pixel cols).
// R27: 4-row tiles (2304 blocks, 15.6KB LDS) for block-level pipelining;
// per-cluster B-loads (taps disjoint per kw) + single-pass staging to cut
// VGPR; register-double-buffered f/B cluster pipeline kept from R26.
__global__ __launch_bounds__(256, 3) void scm_mfma(
    const float* __restrict__ x,
    const ushort* __restrict__ w2,
    const float* __restrict__ bias,
    float* __restrict__ out)
{
    __shared__ ushort xt[6 * 18 * 72];    // 15,552 B

    const int tid  = threadIdx.x;
    const int lane = tid & 63;
    const int wv   = tid >> 6;
    const int col  = lane & 15;           // A-frag m (o) / B-frag n (pixel col)
    const int g    = lane >> 4;           // k-subgroup

    // Flattened grid (2304) + bijective XCD swizzle (2304 % 8 == 0).
    const int bid = blockIdx.x;
    const int lid = (bid & 7) * 288 + (bid >> 3);
    const int b      = lid / 576;
    const int tileid = lid % 576;
    const int ti0 = (tileid / 12) * 4;    // 48 row tiles
    const int tj0 = (tileid % 12) * 16;   // 12 col tiles

    // ---- staging: 6 rows x 18 cols, spatial lanes (54 active), wave-sliced
    // channels, single pass (all 32 loads in flight -> one L2 round-trip).
    // Clamped rows/cols feed only outputs >= 190 (discarded at store).
    {
        const int srr  = lane / 18;       // 0..2
        const int scol = lane - srr * 18; // 0..17
        const bool act = lane < 54;
        int gc = tj0 + scol; if (gc > 191) gc = 191;
        int gr0 = ti0 + srr;     if (gr0 > 191) gr0 = 191;
        int gr1 = ti0 + srr + 3; if (gr1 > 191) gr1 = 191;

        float v[16][2];
        #pragma unroll
        for (int j = 0; j < 16; ++j) {
            const int c = wv * 16 + j;    // wave-uniform channel
            const float* xc = x + ((size_t)(b * NCH + c)) * (HH * WW);
            v[j][0] = xc[gr0 * WW + gc];
            v[j][1] = xc[gr1 * WW + gc];
        }
        __builtin_amdgcn_sched_barrier(0);   // all loads issued before packs
        if (act) {
            #pragma unroll
            for (int pp = 0; pp < 8; ++pp) {
                const int c = wv * 16 + 2 * pp;
                uint k0 = pack2bf(v[2 * pp][0], v[2 * pp + 1][0]);
                uint k1 = pack2bf(v[2 * pp][1], v[2 * pp + 1][1]);
                *(uint*)&xt[((srr    ) * 18 + scol) * 72 + c] = k0;
                *(uint*)&xt[((srr + 3) * 18 + scol) * 72 + c] = k1;
            }
        }
    }
    __syncthreads();

    // ---- compute (operand-swapped), register-double-buffered pipeline.
    f32x4 acc[4];
    #pragma unroll
    for (int i = 0; i < 4; ++i) acc[i] = (f32x4){0.f, 0.f, 0.f, 0.f};

    const ushort* ap0 = &xt[col * 72 + g * 8];
    const ushort* bp  = w2 + (16 * wv + col) * 576 + g * 8;

    bf16x8 fA[6], fB[6];
    bf16x8 BA[3], BB[3];

#define LOADB(B, s, kw) do {                                                   \
        _Pragma("unroll")                                                      \
        for (int _j = 0; _j < 3; ++_j)                                         \
            B[_j] = *(const bf16x8*)(bp + (_j * 3 + (kw)) * 64 + (s) * 32);    \
    } while (0)

#define LOADF(F, s, kw) do {                                                   \
        _Pragma("unroll")                                                      \
        for (int _R = 0; _R < 6; ++_R)                                         \
            F[_R] = *(const bf16x8*)(ap0 + (_R * 18 + (kw)) * 72 + (s) * 32);  \
    } while (0)

#define MFMA12(F, B) do {                                                      \
        _Pragma("unroll")                                                      \
        for (int _Mt = 0; _Mt < 4; ++_Mt) {                                    \
            acc[_Mt] = __builtin_amdgcn_mfma_f32_16x16x32_bf16(B[0], F[_Mt],     acc[_Mt], 0, 0, 0); \
            acc[_Mt] = __builtin_amdgcn_mfma_f32_16x16x32_bf16(B[1], F[_Mt + 1], acc[_Mt], 0, 0, 0); \
            acc[_Mt] = __builtin_amdgcn_mfma_f32_16x16x32_bf16(B[2], F[_Mt + 2], acc[_Mt], 0, 0, 0); \
        }                                                                      \
    } while (0)

    LOADB(BA, 0, 0);  LOADF(fA, 0, 0);
    LOADB(BB, 0, 1);  LOADF(fB, 0, 1);  MFMA12(fA, BA);   // next cluster's loads fly
    LOADB(BA, 0, 2);  LOADF(fA, 0, 2);  MFMA12(fB, BB);
    LOADB(BB, 1, 0);  LOADF(fB, 1, 0);  MFMA12(fA, BA);
    LOADB(BA, 1, 1);  LOADF(fA, 1, 1);  MFMA12(fB, BB);
    LOADB(BB, 1, 2);  LOADF(fB, 1, 2);  MFMA12(fA, BA);
    MFMA12(fB, BB);

#undef LOADB
#undef LOADF
#undef MFMA12

    // ---- epilogue: D col = lane&15 = pixel col (contiguous); D row = o-quad.
    const int pcol = tj0 + col;
    const int obase = 16 * wv + 4 * g;
    float bv[4];
    #pragma unroll
    for (int reg = 0; reg < 4; ++reg) bv[reg] = bias[obase + reg];

    if (pcol < HOUT) {
        #pragma unroll
        for (int Mt = 0; Mt < 4; ++Mt) {
            const int row = ti0 + Mt;
            if (row < HOUT) {
                float* rp = out + ((size_t)(b * NCH + obase) * HOUT + row) * HOUT + pcol;
                #pragma unroll
                for (int reg = 0; reg < 4; ++reg)
                    rp[(size_t)reg * HOUT * HOUT] = acc[Mt][reg] + bv[reg];
            }
        }
    }
}

extern "C" void kernel_launch(void* const* d_in, const int* in_sizes, int n_in,
                              void* d_out, int out_size, void* d_ws, size_t ws_size,
                              hipStream_t stream) {
    const float* x       = (const float*)d_in[0];
    const float* weight  = (const float*)d_in[1];
    const float* bias    = (const float*)d_in[2];
    const int*   conn_in = (const int*)d_in[3];
    // d_in[4] = conn_out (implicit: k -> k/16)

    ushort* w2 = (ushort*)d_ws;   // 73,728 B

    build_w2<<<dim3((W2_N + 255) / 256), dim3(256), 0, stream>>>(weight, conn_in, w2);

    scm_mfma<<<dim3(2304), dim3(256), 0, stream>>>(x, w2, bias, (float*)d_out);
}

// Round 28
// 32.770 us; speedup vs baseline: 1.2444x; 1.2444x over previous
//
#include <hip/hip_runtime.h>
#include <hip/hip_bf16.h>

#define HH 192
#define WW 192
#define HOUT 190
#define NCH 64

typedef __attribute__((ext_vector_type(8))) short bf16x8;
typedef __attribute__((ext_vector_type(4))) float f32x4;

static __device__ __forceinline__ ushort f2bf(float f) {
    __hip_bfloat16 h = __float2bfloat16(f);   // RNE
    return *reinterpret_cast<ushort*>(&h);
}
static __device__ __forceinline__ uint pack2bf(float lo, float hi) {
    return (uint)f2bf(lo) | ((uint)f2bf(hi) << 16);
}

// W2L[tap][s][wv][g][col][j] = sum_t (conn[o*16+t]==c) * w[(o*16+t)*9+tap]
// with o = 16wv+col, c = s*32+g*8+j  — MFMA-A-fragment-ordered so a wave's
// 64 lanes (col fastest, g next) read 1024B CONTIGUOUS per (tap,s).
__global__ __launch_bounds__(256) void build_w2(const float* __restrict__ w,
                                                const int* __restrict__ conn,
                                                ushort* __restrict__ w2l) {
    int idx = blockIdx.x * 256 + threadIdx.x;   // (o, tap, kc) : 64*9*8 = 4608
    if (idx >= 4608) return;
    int o = idx / 72, rem = idx - o * 72, tap = rem >> 3, kc = rem & 7;
    int s = kc >> 2, g = kc & 3, wv = o >> 4, col = o & 15;
    ushort val[8];
    #pragma unroll
    for (int e = 0; e < 8; ++e) {
        int c = kc * 8 + e;
        float sum = 0.f;
        #pragma unroll
        for (int t = 0; t < 16; ++t) {
            int k = o * 16 + t;
            if (conn[k] == c) sum += w[k * 9 + tap];
        }
        val[e] = f2bf(sum);
    }
    uint4 v;
    v.x = (uint)val[0] | ((uint)val[1] << 16);
    v.y = (uint)val[2] | ((uint)val[3] << 16);
    v.z = (uint)val[4] | ((uint)val[5] << 16);
    v.w = (uint)val[6] | ((uint)val[7] << 16);
    size_t off = ((size_t)(tap * 2 + s)) * 2048 + wv * 512 + g * 128 + col * 8;
    *(uint4*)&w2l[off] = v;
}

// Dense 64->64 3x3 conv via mfma_f32_16x16x32_bf16, operand-swapped
// (A = W2 -> D rows = o-quads, D lanes = contiguous pixel cols).
// R28 = R26 + fragment-ordered W2L: B-loads are 1-instruction coalesced
// 1024B wave-reads (was 64-way 1152B-stride scatter = hidden TA serializer).
__global__ __launch_bounds__(256, 3) void scm_mfma(
    const float* __restrict__ x,
    const ushort* __restrict__ w2l,
    const float* __restrict__ bias,
    float* __restrict__ out)
{
    __shared__ ushort xt[10 * 18 * 72];   // 25,920 B

    const int tid  = threadIdx.x;
    const int lane = tid & 63;
    const int wv   = tid >> 6;
    const int col  = lane & 15;           // A-frag m (o) / B-frag n (pixel col)
    const int g    = lane >> 4;           // k-subgroup

    // Flattened grid (1152) + bijective XCD swizzle (1152 % 8 == 0).
    const int bid = blockIdx.x;
    const int lid = (bid & 7) * 144 + (bid >> 3);
    const int b      = lid / 288;
    const int tileid = lid % 288;
    const int ti0 = (tileid / 12) * 8;    // 24 row tiles
    const int tj0 = (tileid % 12) * 16;   // 12 col tiles

    // ---- staging: spatial-lane gather, wave-sliced channels, packed b32 writes.
    {
        const int srr  = lane / 18;       // 0..2 (lanes 54..63: writes masked)
        const int scol = lane - srr * 18; // 0..17
        const bool act = lane < 54;
        int gc = tj0 + scol; if (gc > 191) gc = 191;
        int gr0 = ti0 + srr;     if (gr0 > 191) gr0 = 191;
        int gr1 = ti0 + srr + 3; if (gr1 > 191) gr1 = 191;
        int gr2 = ti0 + srr + 6; if (gr2 > 191) gr2 = 191;
        int gr3 = ti0 + srr + 9; if (gr3 > 191) gr3 = 191;

        #pragma unroll
        for (int pass = 0; pass < 2; ++pass) {
            float v[8][4];
            #pragma unroll
            for (int pj = 0; pj < 8; ++pj) {
                const int c = wv * 16 + pass * 8 + pj;
                const float* xc = x + ((size_t)(b * NCH + c)) * (HH * WW);
                v[pj][0] = xc[gr0 * WW + gc];
                v[pj][1] = xc[gr1 * WW + gc];
                v[pj][2] = xc[gr2 * WW + gc];
                v[pj][3] = xc[gr3 * WW + gc];
            }
            __builtin_amdgcn_sched_barrier(0);   // all 32 loads in flight first
            if (act) {
                #pragma unroll
                for (int pp = 0; pp < 4; ++pp) {
                    const int c = wv * 16 + pass * 8 + 2 * pp;   // even
                    uint k0 = pack2bf(v[2 * pp][0], v[2 * pp + 1][0]);
                    uint k1 = pack2bf(v[2 * pp][1], v[2 * pp + 1][1]);
                    uint k2 = pack2bf(v[2 * pp][2], v[2 * pp + 1][2]);
                    uint k3 = pack2bf(v[2 * pp][3], v[2 * pp + 1][3]);
                    *(uint*)&xt[((srr    ) * 18 + scol) * 72 + c] = k0;
                    *(uint*)&xt[((srr + 3) * 18 + scol) * 72 + c] = k1;
                    *(uint*)&xt[((srr + 6) * 18 + scol) * 72 + c] = k2;
                    if (srr == 0)
                        *(uint*)&xt[(9 * 18 + scol) * 72 + c] = k3;
                }
            }
        }
    }
    __syncthreads();

    // ---- compute (operand-swapped), register-double-buffered pipeline.
    f32x4 acc[8];
    #pragma unroll
    for (int i = 0; i < 8; ++i) acc[i] = (f32x4){0.f, 0.f, 0.f, 0.f};

    const ushort* ap0 = &xt[col * 72 + g * 8];
    const ushort* bpl = w2l + wv * 512 + g * 128 + col * 8;  // lane-contig layout

    bf16x8 fA[10], fB[10];
    bf16x8 Bs[9];

#define LOADB(s) do {                                                          \
        _Pragma("unroll")                                                      \
        for (int _tap = 0; _tap < 9; ++_tap)                                   \
            Bs[_tap] = *(const bf16x8*)(bpl + (_tap * 2 + (s)) * 2048);        \
    } while (0)

#define LOADF(F, s, kw) do {                                                   \
        _Pragma("unroll")                                                      \
        for (int _R = 0; _R < 10; ++_R)                                        \
            F[_R] = *(const bf16x8*)(ap0 + (_R * 18 + (kw)) * 72 + (s) * 32);  \
    } while (0)

#define MFMA24(F, kw) do {                                                     \
        _Pragma("unroll")                                                      \
        for (int _Mt = 0; _Mt < 8; ++_Mt) {                                    \
            acc[_Mt] = __builtin_amdgcn_mfma_f32_16x16x32_bf16(Bs[kw],     F[_Mt],     acc[_Mt], 0, 0, 0); \
            acc[_Mt] = __builtin_amdgcn_mfma_f32_16x16x32_bf16(Bs[3+(kw)], F[_Mt + 1], acc[_Mt], 0, 0, 0); \
            acc[_Mt] = __builtin_amdgcn_mfma_f32_16x16x32_bf16(Bs[6+(kw)], F[_Mt + 2], acc[_Mt], 0, 0, 0); \
        }                                                                      \
    } while (0)

    LOADB(0);
    LOADF(fA, 0, 0);
    LOADF(fB, 0, 1);  MFMA24(fA, 0);     // fB's reads fly under fA's MFMAs
    LOADF(fA, 0, 2);  MFMA24(fB, 1);
    LOADF(fB, 1, 0);  MFMA24(fA, 2);
    LOADB(1);                             // Bs for s=1
    LOADF(fA, 1, 1);  MFMA24(fB, 0);
    LOADF(fB, 1, 2);  MFMA24(fA, 1);
    MFMA24(fB, 2);

#undef LOADB
#undef LOADF
#undef MFMA24

    // ---- epilogue: D col = lane&15 = pixel col (contiguous); D row = o-quad.
    const int pcol = tj0 + col;
    const int obase = 16 * wv + 4 * g;
    float bv[4];
    #pragma unroll
    for (int reg = 0; reg < 4; ++reg) bv[reg] = bias[obase + reg];

    if (pcol < HOUT) {
        #pragma unroll
        for (int Mt = 0; Mt < 8; ++Mt) {
            const int row = ti0 + Mt;
            if (row < HOUT) {
                float* rp = out + ((size_t)(b * NCH + obase) * HOUT + row) * HOUT + pcol;
                #pragma unroll
                for (int reg = 0; reg < 4; ++reg)
                    rp[(size_t)reg * HOUT * HOUT] = acc[Mt][reg] + bv[reg];
            }
        }
    }
}

extern "C" void kernel_launch(void* const* d_in, const int* in_sizes, int n_in,
                              void* d_out, int out_size, void* d_ws, size_t ws_size,
                              hipStream_t stream) {
    const float* x       = (const float*)d_in[0];
    const float* weight  = (const float*)d_in[1];
    const float* bias    = (const float*)d_in[2];
    const int*   conn_in = (const int*)d_in[3];
    // d_in[4] = conn_out (implicit: k -> k/16)

    ushort* w2l = (ushort*)d_ws;   // 73,728 B, fragment-ordered

    build_w2<<<dim3(18), dim3(256), 0, stream>>>(weight, conn_in, w2l);

    scm_mfma<<<dim3(1152), dim3(256), 0, stream>>>(x, w2l, bias, (float*)d_out);
}